// Round 11
// baseline (6338.873 us; speedup 1.0000x reference)
//
#include <hip/hip_runtime.h>
#include <hip/hip_bf16.h>
#include <stdint.h>

#define T_SEQ 128
#define BATCH 64
#define HIDN  256
#define EMB   16
#define VOCAB 16000
#define HSTR  40
#define POIS  0x7FC1          // bf16 NaN — unreachable for h = o*tanh(c)

typedef __attribute__((ext_vector_type(8))) short short8v;
typedef __attribute__((ext_vector_type(4))) float f32x4;
typedef __attribute__((ext_vector_type(4))) int   i32x4;
typedef unsigned short ushort_t;

// ---- ws layout (float units) ----
#define OFF_WC1    0          // ush[1024][256]  reordered Whh1 bf16
#define OFF_WC2    131072     // ush[1024][512]  [Wih2;Whh2] bf16
#define OFF_WC3    393216     // ush[1024][512]
#define OFF_BS2    655360     // f32[1024] bias sums, reordered cols
#define OFF_BS3    656384
#define OFF_XC     657408     // u32[32] XCD-id handshake
#define OFF_W1BF   658432     // ush[256 n][256 k] W1 bf16
#define OFF_H3     723968     // ush[8192][256] bf16 H3 (row m = b*128+t)
#define OFF_S1     2821120    // ush area: [8192][256] bf16
#define OFF_W2BF   3869696    // ush area: [16000][256] bf16

// ---- d_out scratch (float units); dead before k_head2 writes scores ----
#define OUT_XG     0          // f32[128 t][1024 c][64 b]
#define OUT_RINGS  8388608    // ushort base; 6 rings * 2113536
// fwd rings (MALL): l*RING_STRIDE, l=0,1,2 ; local rings (XCD L2): (3+l)*RING_STRIDE
#define RING_STRIDE 2113536
#define SLOT 16384

__device__ __forceinline__ ushort_t f2bf(float x) {
    __hip_bfloat16 h = __float2bfloat16(x);
    return *reinterpret_cast<ushort_t*>(&h);
}

__device__ __forceinline__ float dpp_x1(float x) {   // lane ^ 1 within quad
    return __builtin_bit_cast(float, __builtin_amdgcn_mov_dpp(
        __builtin_bit_cast(int, x), 0xB1, 0xF, 0xF, true));
}
__device__ __forceinline__ float dpp_x2(float x) {   // lane ^ 2 within quad
    return __builtin_bit_cast(float, __builtin_amdgcn_mov_dpp(
        __builtin_bit_cast(int, x), 0x4E, 0xF, 0xF, true));
}
__device__ __forceinline__ f32x4 dpp4_x1(f32x4 v) {
    f32x4 r; r[0]=dpp_x1(v[0]); r[1]=dpp_x1(v[1]); r[2]=dpp_x1(v[2]); r[3]=dpp_x1(v[3]); return r;
}
__device__ __forceinline__ f32x4 dpp4_x2(f32x4 v) {
    f32x4 r; r[0]=dpp_x2(v[0]); r[1]=dpp_x2(v[1]); r[2]=dpp_x2(v[2]); r[3]=dpp_x2(v[3]); return r;
}

// MALL-bypass (cross-XCD) ops
__device__ __forceinline__ i32x4 mall_ld128(const void* p) {
    i32x4 v;
    asm volatile("global_load_dwordx4 %0, %1, off sc0 sc1" : "=v"(v) : "v"((uint64_t)p));
    return v;
}
__device__ __forceinline__ void mall_st128(void* p, f32x4 v) {
    asm volatile("global_store_dwordx4 %0, %1, off sc0 sc1" :: "v"((uint64_t)p), "v"(v) : "memory");
}
__device__ __forceinline__ unsigned int mall_ld32(const void* p) {
    unsigned int v;
    asm volatile("global_load_dword %0, %1, off sc0 sc1" : "=v"(v) : "v"((uint64_t)p));
    return v;
}
__device__ __forceinline__ void mall_st32(void* p, unsigned int v) {
    asm volatile("global_store_dword %0, %1, off sc0 sc1" :: "v"((uint64_t)p), "v"(v) : "memory");
}
// intra-XCD (shared L2) ops: bypass L1 only — used ONLY after runtime
// verification that producer+consumer share an XCD (never load-bearing:
// bounded-retry falls back to the always-written MALL fwd ring)
__device__ __forceinline__ i32x4 l2_ld128(const void* p) {
    i32x4 v;
    asm volatile("global_load_dwordx4 %0, %1, off sc0" : "=v"(v) : "v"((uint64_t)p));
    return v;
}
__device__ __forceinline__ void l2_st128(void* p, f32x4 v) {
    asm volatile("global_store_dwordx4 %0, %1, off sc0" :: "v"((uint64_t)p), "v"(v) : "memory");
}
__device__ __forceinline__ void vm_drain() {
    asm volatile("s_waitcnt vmcnt(0)" ::: "memory");
    __builtin_amdgcn_sched_barrier(0);
}
__device__ __forceinline__ void lgkm_drain() {
    asm volatile("s_waitcnt lgkmcnt(0)" ::: "memory");
    __builtin_amdgcn_sched_barrier(0);
}

// ---------------- prep kernels ----------------
// poison ring slots 1..128 of all 6 rings with bf16 NaN (sentinel protocol)
__global__ void k_poison(ushort_t* __restrict__ rbase) {
    unsigned int u = blockIdx.x * 256 + threadIdx.x;      // < 6*128*8192 u32
    unsigned int l = u >> 20;                              // ring 0..5
    unsigned int r = u & 1048575;
    unsigned int s = 1 + (r >> 13);
    unsigned int off = r & 8191;
    ((unsigned int*)(rbase + (size_t)l * RING_STRIDE + (size_t)s * SLOT))[off] = 0x7FC17FC1u;
}

__global__ void k_xc_reset(float* wsf) {
    if (threadIdx.x < 32) ((unsigned int*)(wsf + OFF_XC))[threadIdx.x] = 0;
}

__global__ void k_reorder_w(const float* __restrict__ Whh1,
                            const float* __restrict__ Wih2, const float* __restrict__ Whh2,
                            const float* __restrict__ Wih3, const float* __restrict__ Whh3,
                            float* __restrict__ wsf) {
    int bid = blockIdx.x;                 // 0..3071
    int layer = bid >> 10, c = bid & 1023;
    int wgi = c >> 7, rr = c & 127, jl = rr >> 2, gg = rr & 3;
    int row = gg * 256 + wgi * 32 + jl;
    int tid = threadIdx.x;
    if (layer == 0) {
        ushort_t* dst = (ushort_t*)(wsf + OFF_WC1) + (size_t)c * 256;
        dst[tid] = f2bf(Whh1[row * 256 + tid]);
    } else {
        const float* Wi = (layer == 1) ? Wih2 : Wih3;
        const float* Wh = (layer == 1) ? Whh2 : Whh3;
        ushort_t* dst = (ushort_t*)(wsf + ((layer == 1) ? OFF_WC2 : OFF_WC3)) + (size_t)c * 512;
        for (int k = tid; k < 512; k += 256)
            dst[k] = f2bf(k < 256 ? Wi[row * 256 + k] : Wh[row * 256 + k - 256]);
    }
}

__global__ void k_bias23(const float* __restrict__ bi2, const float* __restrict__ bh2,
                         const float* __restrict__ bi3, const float* __restrict__ bh3,
                         float* __restrict__ wsf) {
    int idx = blockIdx.x * 256 + threadIdx.x;   // 0..2047
    int layer = idx >> 10, c = idx & 1023;
    int wgi = c >> 7, rr = c & 127, jl = rr >> 2, gg = rr & 3;
    int row = gg * 256 + wgi * 32 + jl;
    wsf[((layer == 0) ? OFF_BS2 : OFF_BS3) + c] =
        (layer == 0) ? (bi2[row] + bh2[row]) : (bi3[row] + bh3[row]);
}

// Xg[t][c_new][b] = emb[tok[b,t]] . Wih1[row(c_new)] + bih1[row] + bhh1[row]
__global__ void k_xg(const int* __restrict__ tokens, const float* __restrict__ emb,
                     const float* __restrict__ Wih1, const float* __restrict__ bih1,
                     const float* __restrict__ bhh1, float* __restrict__ xg) {
    int t = blockIdx.x, cg = blockIdx.y;
    int tid = threadIdx.x;
    __shared__ float xs[64][16];
    for (int idx = tid; idx < 1024; idx += 256) {
        int b = idx >> 4, e = idx & 15;
        xs[b][e] = emb[(size_t)tokens[b * T_SEQ + t] * 16 + e];
    }
    __syncthreads();
    int c = cg * 64 + (tid & 63);
    int b0 = (tid >> 6) * 16;
    int wgi = c >> 7, rr = c & 127, jl = rr >> 2, gg = rr & 3;
    int row = gg * 256 + wgi * 32 + jl;
    float wv[16];
    #pragma unroll
    for (int e = 0; e < 16; ++e) wv[e] = Wih1[row * 16 + e];
    float bias = bih1[row] + bhh1[row];
    float* dst = xg + ((size_t)t * 1024 + c) * 64 + b0;
    for (int b = 0; b < 16; ++b) {
        float s = bias;
        #pragma unroll
        for (int e = 0; e < 16; ++e) s += xs[b0 + b][e] * wv[e];
        dst[b] = s;
    }
}

__global__ void k_init_rings(const float* __restrict__ h0, ushort_t* __restrict__ rbase) {
    int idx = blockIdx.x * 256 + threadIdx.x;   // 16384
    ushort_t v = f2bf(h0[idx]);
    #pragma unroll
    for (int l = 0; l < 6; ++l)
        rbase[(size_t)l * RING_STRIDE + idx] = v;
}

__global__ void k_conv_w1(const float* __restrict__ W1, ushort_t* __restrict__ dst) {
    int idx = blockIdx.x * 256 + threadIdx.x;   // 65536
    dst[idx] = f2bf(W1[idx]);
}

// vectorized f32 -> bf16 conversion, 8 elems/thread
__global__ void k_conv_w2(const float* __restrict__ src, ushort_t* __restrict__ dst, int n8) {
    int idx = blockIdx.x * 256 + threadIdx.x;
    if (idx < n8) {
        f32x4 a = *(const f32x4*)(src + (size_t)idx * 8);
        f32x4 b = *(const f32x4*)(src + (size_t)idx * 8 + 4);
        short8v o;
        o[0] = (short)f2bf(a[0]); o[1] = (short)f2bf(a[1]);
        o[2] = (short)f2bf(a[2]); o[3] = (short)f2bf(a[3]);
        o[4] = (short)f2bf(b[0]); o[5] = (short)f2bf(b[1]);
        o[6] = (short)f2bf(b[2]); o[7] = (short)f2bf(b[3]);
        *(short8v*)(dst + (size_t)idx * 8) = o;
    }
}

// ---------------- persistent pipelined scan (sentinel + verified XCD-local) ---
template<int LAYER, int NKS>
__device__ __forceinline__ void lstm_body(
    int wg, int tid, const float* __restrict__ c0,
    float* __restrict__ wsf, float* __restrict__ outf,
    ushort_t* hA, ushort_t* hB, ushort_t* hS) {
    const int w = tid >> 6, lane = tid & 63, lr = lane & 15, lg = lane >> 4;
    const int g = lr & 3;
    const int K = NKS * 32;
    const ushort_t* WC = (const ushort_t*)(wsf + (LAYER == 0 ? OFF_WC1 : LAYER == 1 ? OFF_WC2 : OFF_WC3));
    ushort_t* H3b = (ushort_t*)(wsf + OFF_H3);
    const float* xg = outf + OUT_XG;
    ushort_t* rbase = (ushort_t*)(outf + OUT_RINGS);
    ushort_t* ringFwdIn  = rbase + (size_t)(LAYER == 0 ? 0 : LAYER - 1) * RING_STRIDE;
    ushort_t* ringFwdOwn = rbase + (size_t)LAYER * RING_STRIDE;
    ushort_t* ringLocOwn = rbase + (size_t)(3 + LAYER) * RING_STRIDE;
    unsigned int* XC = (unsigned int*)(wsf + OFF_XC);

    // ---- runtime XCD co-placement detection (bounded; never load-bearing) ----
    __shared__ int s_localok;
    {
        if (tid == 0) {
            unsigned int xcc;
            asm volatile("s_getreg_b32 %0, hwreg(HW_REG_XCC_ID)" : "=s"(xcc));
            mall_st32(&XC[LAYER * 8 + wg], xcc + 1);
        }
        if (tid < 8) {
            unsigned int v;
            do { v = mall_ld32(&XC[LAYER * 8 + tid]); vm_drain(); } while (v == 0);
            unsigned int v0 = __shfl(v, 0);
            unsigned long long eq = __ballot(v == v0);
            if (tid == 0) s_localok = ((eq & 0xFFull) == 0xFFull) ? 1 : 0;
        }
        __syncthreads();
    }
    int localok = s_localok;

    const int ccol = wg * 128 + 2 * w * 16 + lr;
    short8v wr0[NKS], wr1[NKS];
    #pragma unroll
    for (int ks = 0; ks < NKS; ++ks) {
        wr0[ks] = *(const short8v*)(WC + (size_t)ccol * K + ks * 32 + lg * 8);
        wr1[ks] = *(const short8v*)(WC + (size_t)(ccol + 16) * K + ks * 32 + lg * 8);
    }
    float bs0 = 0.f, bs1 = 0.f;
    if (LAYER > 0) {
        const float* BS = wsf + (LAYER == 1 ? OFF_BS2 : OFF_BS3);
        bs0 = BS[ccol]; bs1 = BS[ccol + 16];
    }
    const int jj0 = w * 8 + (lr >> 2);
    const int j0 = wg * 32 + jj0;
    f32x4 cst[4][2];
    #pragma unroll
    for (int i = 0; i < 4; ++i)
        #pragma unroll
        for (int r = 0; r < 4; ++r) {
            cst[i][0][r] = c0[(i * 16 + lg * 4 + r) * 256 + j0];
            cst[i][1][r] = c0[(i * 16 + lg * 4 + r) * 256 + j0 + 4];
        }
    const float sOwn = (g == 2) ? 2.f : -1.f;
    const float aOwn = (g == 2) ? -2.f : 1.f;
    const float bOwn = (g == 2) ? 1.f : 0.f;

    for (int t = 0; t < T_SEQ; ++t) {
        // ---- prefetch Xg (flag-independent; hides HBM latency) ----
        f32x4 xpre[8];
        if (LAYER == 0) {
            const float* xt = xg + ((size_t)t * 1024 + wg * 128) * 64;
            #pragma unroll
            for (int i = 0; i < 4; ++i) {
                xpre[i]     = *(const f32x4*)(xt + (size_t)(2 * w * 16 + lr) * 64 + i * 16 + lg * 4);
                xpre[i + 4] = *(const f32x4*)(xt + (size_t)((2 * w + 1) * 16 + lr) * 64 + i * 16 + lg * 4);
            }
        }
        i32x4 ta[8], tb[8];
        // ---- input ring (L>0; MALL, run-ahead so usually first-try) ----
        if (LAYER > 0) {
            const char* sIn = (const char*)(ringFwdIn + (size_t)(t + 1) * SLOT);
            for (;;) {
                #pragma unroll
                for (int it = 0; it < 8; ++it)
                    tb[it] = mall_ld128(sIn + it * 4096 + tid * 16);
                vm_drain();
                int p = 0;
                #pragma unroll
                for (int it = 0; it < 8; ++it)
                    p |= ((tb[it][0] & 0xFFFF) == POIS);
                if (!__any(p)) break;
            }
        }
        // ---- own ring: L2-local if verified, MALL fwd otherwise/fallback ----
        {
            const char* sLoc = (const char*)(ringLocOwn + (size_t)t * SLOT);
            const char* sFwd = (const char*)(ringFwdOwn + (size_t)t * SLOT);
            int tries = 0;
            for (;;) {
                if (localok) {
                    #pragma unroll
                    for (int it = 0; it < 8; ++it)
                        ta[it] = l2_ld128(sLoc + it * 4096 + tid * 16);
                } else {
                    #pragma unroll
                    for (int it = 0; it < 8; ++it)
                        ta[it] = mall_ld128(sFwd + it * 4096 + tid * 16);
                }
                vm_drain();
                int p = 0;
                #pragma unroll
                for (int it = 0; it < 8; ++it)
                    p |= ((ta[it][0] & 0xFFFF) == POIS);
                if (!__any(p)) break;
                if (localok && ++tries > 4096) localok = 0;   // uniform latch -> fwd ring
            }
        }
        __syncthreads();     // all waves done reading hA/hB of previous step
        // ---- restage to LDS (XOR swizzle) ----
        #pragma unroll
        for (int it = 0; it < 8; ++it) {
            int e16 = it * 256 + tid;
            int row = e16 >> 5, c16 = e16 & 31;
            int off = row * 512 + ((c16 ^ (row & 15)) << 4);
            *(i32x4*)((char*)hA + off) = ta[it];
            if (LAYER > 0) *(i32x4*)((char*)hB + off) = tb[it];
        }
        __syncthreads();
        // ---- acc init ----
        f32x4 acc[4][2];
        if (LAYER == 0) {
            #pragma unroll
            for (int i = 0; i < 4; ++i) { acc[i][0] = xpre[i]; acc[i][1] = xpre[i + 4]; }
        } else {
            #pragma unroll
            for (int i = 0; i < 4; ++i) {
                acc[i][0] = (f32x4){bs0, bs0, bs0, bs0};
                acc[i][1] = (f32x4){bs1, bs1, bs1, bs1};
            }
        }
        // ---- MFMA: gates += h_cat @ Wcat^T ----
        #pragma unroll
        for (int i = 0; i < 4; ++i) {
            #pragma unroll
            for (int ks = 0; ks < NKS; ++ks) {
                const ushort_t* hsrc = (ks < 8) ? ((NKS == 16) ? hB : hA) : hA;
                const int krem = ks & 7;
                short8v a = *(const short8v*)((const char*)hsrc + (i * 16 + lr) * 512 +
                                              (((krem * 4 + lg) ^ lr) << 4));
                acc[i][0] = __builtin_amdgcn_mfma_f32_16x16x32_bf16(a, wr0[ks], acc[i][0], 0, 0, 0);
                acc[i][1] = __builtin_amdgcn_mfma_f32_16x16x32_bf16(a, wr1[ks], acc[i][1], 0, 0, 0);
            }
        }
        // ---- activations (own-gate act + DPP gather; scalar tanh own row) ----
        #pragma unroll
        for (int i = 0; i < 4; ++i) {
            #pragma unroll
            for (int f = 0; f < 2; ++f) {
                f32x4 av = acc[i][f];
                f32x4 act;
                #pragma unroll
                for (int r = 0; r < 4; ++r) {
                    float e = __expf(sOwn * av[r]);
                    act[r] = fmaf(aOwn, __builtin_amdgcn_rcpf(1.f + e), bOwn);
                }
                f32x4 q1 = dpp4_x1(act), q2 = dpp4_x2(act), q3 = dpp4_x1(q2);
                f32x4 gI = (g == 0) ? act : (g == 1) ? q1 : (g == 2) ? q2 : q3;
                f32x4 gF = (g == 1) ? act : (g == 0) ? q1 : (g == 3) ? q2 : q3;
                f32x4 gG = (g == 2) ? act : (g == 3) ? q1 : (g == 0) ? q2 : q3;
                f32x4 gO = (g == 3) ? act : (g == 2) ? q1 : (g == 1) ? q2 : q3;
                f32x4 cv = gF * cst[i][f] + gI * gG;
                cst[i][f] = cv;
                float cg = (g == 0) ? cv[0] : (g == 1) ? cv[1] : (g == 2) ? cv[2] : cv[3];
                float go = (g == 0) ? gO[0] : (g == 1) ? gO[1] : (g == 2) ? gO[2] : gO[3];
                float e2 = __expf(2.f * cg);
                float th = fmaf(-2.f, __builtin_amdgcn_rcpf(1.f + e2), 1.f);
                float hval = go * th;
                int brow = i * 16 + lg * 4 + g;
                hS[brow * HSTR + jj0 + f * 4] = f2bf(hval);
            }
        }
        lgkm_drain();
        // ---- readback; dual-store: local (L2) + fwd (MALL, always) ----
        {
            f32x4 hv4 = *(const f32x4*)((const char*)hS + lane * (HSTR * 2) + w * 16);
            size_t soff = (size_t)(t + 1) * SLOT + (size_t)lane * 256 + wg * 32 + w * 8;
            l2_st128(ringLocOwn + soff, hv4);
            mall_st128(ringFwdOwn + soff, hv4);
            if (LAYER == 2)
                *(f32x4*)(H3b + (((size_t)lane * 128 + t) * 256 + wg * 32 + w * 8)) = hv4;
        }
        // sentinel protocol — no drain, no flag
    }
}

__global__ __launch_bounds__(256, 1) void k_lstm(const float* __restrict__ c0,
                                                 float* __restrict__ wsf,
                                                 float* __restrict__ outf) {
    __shared__ __align__(16) ushort_t hA[16384];
    __shared__ __align__(16) ushort_t hB[16384];
    __shared__ __align__(16) ushort_t hS[64 * HSTR];
    // 64 wgs; layer = bid%8 (<3 active), wg = bid>>3 — targets layer-l-on-XCD-l
    // under round-robin dispatch; detection verifies, fallback keeps correctness.
    int layer = blockIdx.x & 7, wg = blockIdx.x >> 3;
    if (layer >= 3) return;
    if (layer == 0)      lstm_body<0, 8>(wg, threadIdx.x, c0, wsf, outf, hA, hB, hS);
    else if (layer == 1) lstm_body<1, 16>(wg, threadIdx.x, c0, wsf, outf, hA, hB, hS);
    else                 lstm_body<2, 16>(wg, threadIdx.x, c0, wsf, outf, hA, hB, hS);
}

// ---------- head GEMM1 (MFMA): S1 = relu(H3 @ W1^T + b1) -> bf16 ----------
__global__ __launch_bounds__(256) void k_head1m(const ushort_t* __restrict__ H3,
                                                const ushort_t* __restrict__ W1B,
                                                const float* __restrict__ b1,
                                                ushort_t* __restrict__ S1) {
    __shared__ __align__(16) ushort_t As[128][32];
    __shared__ __align__(16) ushort_t Bs[128][32];
    int tid = threadIdx.x;
    int n0 = blockIdx.x * 128;
    int m0 = blockIdx.y * 128;
    int wave = tid >> 6, lane = tid & 63;
    int lr = lane & 15, lg = lane >> 4;
    int wm = (wave >> 1) * 64, wn = (wave & 1) * 64;
    f32x4 acc[4][4] = {};

    for (int kk = 0; kk < 256; kk += 32) {
        int id = tid;
        #pragma unroll
        for (int rep = 0; rep < 2; ++rep, id += 256) {
            int r = id >> 2, ch = (id & 3) * 8;
            *(short8v*)(&As[r][ch]) = *(const short8v*)(H3 + (size_t)(m0 + r) * 256 + kk + ch);
            *(short8v*)(&Bs[r][ch]) = *(const short8v*)(W1B + (size_t)(n0 + r) * 256 + kk + ch);
        }
        __syncthreads();
        short8v a[4], bb[4];
        #pragma unroll
        for (int i = 0; i < 4; ++i) a[i]  = *(const short8v*)(&As[wm + i * 16 + lr][lg * 8]);
        #pragma unroll
        for (int i = 0; i < 4; ++i) bb[i] = *(const short8v*)(&Bs[wn + i * 16 + lr][lg * 8]);
        #pragma unroll
        for (int i = 0; i < 4; ++i)
            #pragma unroll
            for (int f = 0; f < 4; ++f)
                acc[i][f] = __builtin_amdgcn_mfma_f32_16x16x32_bf16(a[i], bb[f], acc[i][f], 0, 0, 0);
        __syncthreads();
    }
    #pragma unroll
    for (int f = 0; f < 4; ++f) {
        int col = n0 + wn + f * 16 + lr;
        float bias = b1[col];
        #pragma unroll
        for (int i = 0; i < 4; ++i) {
            int rowb = m0 + wm + i * 16 + lg * 4;
            #pragma unroll
            for (int r = 0; r < 4; ++r)
                S1[(size_t)(rowb + r) * 256 + col] = f2bf(fmaxf(acc[i][f][r] + bias, 0.f));
        }
    }
}

// ---------- head GEMM2: scores = S1 @ W2^T + b2 ----------
__global__ __launch_bounds__(256) void k_head2(const ushort_t* __restrict__ S1,
                                               const ushort_t* __restrict__ W2,
                                               const float* __restrict__ b2, float* __restrict__ out) {
    __shared__ __align__(16) ushort_t As[128][32];
    __shared__ __align__(16) ushort_t Bs[128][32];
    int tid = threadIdx.x;
    int n0 = blockIdx.x * 128;
    int m0 = blockIdx.y * 128;
    int wave = tid >> 6, lane = tid & 63;
    int lr = lane & 15, lg = lane >> 4;
    int wm = (wave >> 1) * 64, wn = (wave & 1) * 64;
    f32x4 acc[4][4] = {};

    for (int kk = 0; kk < 256; kk += 32) {
        int id = tid;
        #pragma unroll
        for (int rep = 0; rep < 2; ++rep, id += 256) {
            int r = id >> 2, ch = (id & 3) * 8;
            *(short8v*)(&As[r][ch]) = *(const short8v*)(S1 + (size_t)(m0 + r) * 256 + kk + ch);
            *(short8v*)(&Bs[r][ch]) = *(const short8v*)(W2 + (size_t)(n0 + r) * 256 + kk + ch);
        }
        __syncthreads();
        short8v a[4], bb[4];
        #pragma unroll
        for (int i = 0; i < 4; ++i) a[i]  = *(const short8v*)(&As[wm + i * 16 + lr][lg * 8]);
        #pragma unroll
        for (int i = 0; i < 4; ++i) bb[i] = *(const short8v*)(&Bs[wn + i * 16 + lr][lg * 8]);
        #pragma unroll
        for (int i = 0; i < 4; ++i)
            #pragma unroll
            for (int f = 0; f < 4; ++f)
                acc[i][f] = __builtin_amdgcn_mfma_f32_16x16x32_bf16(a[i], bb[f], acc[i][f], 0, 0, 0);
        __syncthreads();
    }
    #pragma unroll
    for (int f = 0; f < 4; ++f) {
        int col = n0 + wn + f * 16 + lr;
        float bias = b2[col];
        #pragma unroll
        for (int i = 0; i < 4; ++i) {
            int rowb = m0 + wm + i * 16 + lg * 4;
            #pragma unroll
            for (int r = 0; r < 4; ++r)
                out[(size_t)(rowb + r) * VOCAB + col] = acc[i][f][r] + bias;
        }
    }
}

__global__ void k_labels(const int* __restrict__ tokens, float* __restrict__ out) {
    int i = blockIdx.x * 256 + threadIdx.x;
    if (i < BATCH * T_SEQ) out[i] = (float)tokens[i];
}

extern "C" void kernel_launch(void* const* d_in, const int* in_sizes, int n_in,
                              void* d_out, int out_size, void* d_ws, size_t ws_size,
                              hipStream_t stream) {
    const int*   tokens = (const int*)d_in[0];
    const float* h0   = (const float*)d_in[1];
    const float* c0   = (const float*)d_in[2];
    const float* emb  = (const float*)d_in[3];
    const float* Wih1 = (const float*)d_in[4];
    const float* Whh1 = (const float*)d_in[5];
    const float* bih1 = (const float*)d_in[6];
    const float* bhh1 = (const float*)d_in[7];
    const float* Wih2 = (const float*)d_in[8];
    const float* Whh2 = (const float*)d_in[9];
    const float* bih2 = (const float*)d_in[10];
    const float* bhh2 = (const float*)d_in[11];
    const float* Wih3 = (const float*)d_in[12];
    const float* Whh3 = (const float*)d_in[13];
    const float* bih3 = (const float*)d_in[14];
    const float* bhh3 = (const float*)d_in[15];
    const float* W1   = (const float*)d_in[16];
    const float* b1   = (const float*)d_in[17];
    const float* W2   = (const float*)d_in[18];
    const float* b2   = (const float*)d_in[19];

    float* ws  = (float*)d_ws;
    float* out = (float*)d_out;

    k_poison<<<24576, 256, 0, stream>>>((ushort_t*)(out + OUT_RINGS));
    k_xc_reset<<<1, 64, 0, stream>>>(ws);
    k_reorder_w<<<3072, 256, 0, stream>>>(Whh1, Wih2, Whh2, Wih3, Whh3, ws);
    k_bias23<<<8, 256, 0, stream>>>(bih2, bhh2, bih3, bhh3, ws);
    k_xg<<<dim3(128, 16), 256, 0, stream>>>(tokens, emb, Wih1, bih1, bhh1, out + OUT_XG);
    k_init_rings<<<64, 256, 0, stream>>>(h0, (ushort_t*)(out + OUT_RINGS));
    k_conv_w1<<<256, 256, 0, stream>>>(W1, (ushort_t*)(ws + OFF_W1BF));
    k_conv_w2<<<2000, 256, 0, stream>>>(W2, (ushort_t*)(ws + OFF_W2BF), VOCAB * 256 / 8);

    k_lstm<<<64, 256, 0, stream>>>(c0, ws, out);

    dim3 g1(2, 64);
    k_head1m<<<g1, 256, 0, stream>>>((const ushort_t*)(ws + OFF_H3),
                                     (const ushort_t*)(ws + OFF_W1BF), b1,
                                     (ushort_t*)(ws + OFF_S1));
    dim3 g2(125, 64);
    k_head2<<<g2, 256, 0, stream>>>((const ushort_t*)(ws + OFF_S1),
                                    (const ushort_t*)(ws + OFF_W2BF), b2, out);
    k_labels<<<32, 256, 0, stream>>>(tokens, out + (size_t)BATCH * T_SEQ * VOCAB);
}

// Round 12
// 1090.407 us; speedup vs baseline: 5.8133x; 5.8133x over previous
//
#include <hip/hip_runtime.h>
#include <hip/hip_bf16.h>
#include <stdint.h>

#define T_SEQ 128
#define BATCH 64
#define HIDN  256
#define EMB   16
#define VOCAB 16000
#define HSTR  40
#define POIS  0x7FC1          // bf16 NaN — unreachable for h = o*tanh(c)

typedef __attribute__((ext_vector_type(8))) short short8v;
typedef __attribute__((ext_vector_type(4))) float f32x4;
typedef __attribute__((ext_vector_type(4))) int   i32x4;
typedef unsigned short ushort_t;

// ---- ws layout (float units) ----
#define OFF_WC1    0          // ush[1024][256]  reordered Whh1 bf16
#define OFF_WC2    131072     // ush[1024][512]  [Wih2;Whh2] bf16
#define OFF_WC3    393216     // ush[1024][512]
#define OFF_BS2    655360     // f32[1024] bias sums, reordered cols
#define OFF_BS3    656384
#define OFF_W1BF   658432     // ush[256 n][256 k] W1 bf16
#define OFF_H3     723968     // ush[8192][256] bf16 H3 (row m = b*128+t)
#define OFF_S1     2821120    // ush area: [8192][256] bf16
#define OFF_W2BF   3869696    // ush area: [16000][256] bf16

// ---- d_out scratch (float units); dead before k_head2 writes scores ----
#define OUT_XG     0          // f32[128 t][1024 c][64 b]
#define OUT_RINGS  8388608    // ushort base; ring l at l*2113536; 129 slots * 16384

#define RING_STRIDE 2113536
#define SLOT 16384

__device__ __forceinline__ ushort_t f2bf(float x) {
    __hip_bfloat16 h = __float2bfloat16(x);
    return *reinterpret_cast<ushort_t*>(&h);
}

__device__ __forceinline__ float dpp_x1(float x) {   // lane ^ 1 within quad
    return __builtin_bit_cast(float, __builtin_amdgcn_mov_dpp(
        __builtin_bit_cast(int, x), 0xB1, 0xF, 0xF, true));
}
__device__ __forceinline__ float dpp_x2(float x) {   // lane ^ 2 within quad
    return __builtin_bit_cast(float, __builtin_amdgcn_mov_dpp(
        __builtin_bit_cast(int, x), 0x4E, 0xF, 0xF, true));
}
__device__ __forceinline__ f32x4 dpp4_x1(f32x4 v) {
    f32x4 r; r[0]=dpp_x1(v[0]); r[1]=dpp_x1(v[1]); r[2]=dpp_x1(v[2]); r[3]=dpp_x1(v[3]); return r;
}
__device__ __forceinline__ f32x4 dpp4_x2(f32x4 v) {
    f32x4 r; r[0]=dpp_x2(v[0]); r[1]=dpp_x2(v[1]); r[2]=dpp_x2(v[2]); r[3]=dpp_x2(v[3]); return r;
}

// pipelined MALL-bypass 16B load (no wait; caller drains vmcnt)
__device__ __forceinline__ i32x4 bypass_ld128(const void* p) {
    i32x4 v;
    asm volatile("global_load_dwordx4 %0, %1, off sc0 sc1" : "=v"(v) : "v"((uint64_t)p));
    return v;
}
// write-through MALL-bypass 16B store
__device__ __forceinline__ void bypass_st128(void* p, f32x4 v) {
    asm volatile("global_store_dwordx4 %0, %1, off sc0 sc1" :: "v"((uint64_t)p), "v"(v) : "memory");
}
// non-temporal 16B store (write-once streaming output; don't pollute LLC)
__device__ __forceinline__ void nt_st128(void* p, f32x4 v) {
    asm volatile("global_store_dwordx4 %0, %1, off nt" :: "v"((uint64_t)p), "v"(v) : "memory");
}
__device__ __forceinline__ void vm_drain() {
    asm volatile("s_waitcnt vmcnt(0)" ::: "memory");
    __builtin_amdgcn_sched_barrier(0);
}
__device__ __forceinline__ void lgkm_drain() {
    asm volatile("s_waitcnt lgkmcnt(0)" ::: "memory");
    __builtin_amdgcn_sched_barrier(0);
}

// ---------------- prep kernels ----------------
// poison ring slots 1..128 of all 3 rings with bf16 NaN (sentinel protocol)
__global__ void k_poison(ushort_t* __restrict__ rbase) {
    unsigned int u = blockIdx.x * 256 + threadIdx.x;      // < 3*128*8192
    unsigned int l = u >> 20;                              // / 1048576
    unsigned int r = u & 1048575;
    unsigned int s = 1 + (r >> 13);
    unsigned int off = r & 8191;
    ((unsigned int*)(rbase + (size_t)l * RING_STRIDE + (size_t)s * SLOT))[off] = 0x7FC17FC1u;
}

__global__ void k_reorder_w(const float* __restrict__ Whh1,
                            const float* __restrict__ Wih2, const float* __restrict__ Whh2,
                            const float* __restrict__ Wih3, const float* __restrict__ Whh3,
                            float* __restrict__ wsf) {
    int bid = blockIdx.x;                 // 0..3071
    int layer = bid >> 10, c = bid & 1023;
    int wgi = c >> 7, rr = c & 127, jl = rr >> 2, gg = rr & 3;
    int row = gg * 256 + wgi * 32 + jl;
    int tid = threadIdx.x;
    if (layer == 0) {
        ushort_t* dst = (ushort_t*)(wsf + OFF_WC1) + (size_t)c * 256;
        dst[tid] = f2bf(Whh1[row * 256 + tid]);
    } else {
        const float* Wi = (layer == 1) ? Wih2 : Wih3;
        const float* Wh = (layer == 1) ? Whh2 : Whh3;
        ushort_t* dst = (ushort_t*)(wsf + ((layer == 1) ? OFF_WC2 : OFF_WC3)) + (size_t)c * 512;
        for (int k = tid; k < 512; k += 256)
            dst[k] = f2bf(k < 256 ? Wi[row * 256 + k] : Wh[row * 256 + k - 256]);
    }
}

// merged small preps: bias sums (blocks 0..7) + ring slot-0 init (8..71)
// + W1 bf16 conversion (72..327)
__global__ void k_prep_small(const float* __restrict__ bi2, const float* __restrict__ bh2,
                             const float* __restrict__ bi3, const float* __restrict__ bh3,
                             const float* __restrict__ h0, const float* __restrict__ W1,
                             float* __restrict__ wsf, ushort_t* __restrict__ rbase) {
    int bid = blockIdx.x, tid = threadIdx.x;
    if (bid < 8) {
        int idx = bid * 256 + tid;                // < 2048
        int layer = idx >> 10, c = idx & 1023;
        int wgi = c >> 7, rr = c & 127, jl = rr >> 2, gg = rr & 3;
        int row = gg * 256 + wgi * 32 + jl;
        wsf[((layer == 0) ? OFF_BS2 : OFF_BS3) + c] =
            (layer == 0) ? (bi2[row] + bh2[row]) : (bi3[row] + bh3[row]);
    } else if (bid < 72) {
        int idx = (bid - 8) * 256 + tid;          // < 16384
        ushort_t v = f2bf(h0[idx]);
        rbase[idx] = v;
        rbase[RING_STRIDE + idx] = v;
        rbase[2 * RING_STRIDE + idx] = v;
    } else {
        int idx = (bid - 72) * 256 + tid;         // < 65536
        ((ushort_t*)(wsf + OFF_W1BF))[idx] = f2bf(W1[idx]);
    }
}

// Xg[t][c_new][b] = emb[tok[b,t]] . Wih1[row(c_new)] + bih1[row] + bhh1[row]
__global__ void k_xg(const int* __restrict__ tokens, const float* __restrict__ emb,
                     const float* __restrict__ Wih1, const float* __restrict__ bih1,
                     const float* __restrict__ bhh1, float* __restrict__ xg) {
    int t = blockIdx.x, cg = blockIdx.y;
    int tid = threadIdx.x;
    __shared__ float xs[64][16];
    for (int idx = tid; idx < 1024; idx += 256) {
        int b = idx >> 4, e = idx & 15;
        xs[b][e] = emb[(size_t)tokens[b * T_SEQ + t] * 16 + e];
    }
    __syncthreads();
    int c = cg * 64 + (tid & 63);
    int b0 = (tid >> 6) * 16;
    int wgi = c >> 7, rr = c & 127, jl = rr >> 2, gg = rr & 3;
    int row = gg * 256 + wgi * 32 + jl;
    float wv[16];
    #pragma unroll
    for (int e = 0; e < 16; ++e) wv[e] = Wih1[row * 16 + e];
    float bias = bih1[row] + bhh1[row];
    float* dst = xg + ((size_t)t * 1024 + c) * 64 + b0;
    for (int b = 0; b < 16; ++b) {
        float s = bias;
        #pragma unroll
        for (int e = 0; e < 16; ++e) s += xs[b0 + b][e] * wv[e];
        dst[b] = s;
    }
}

// vectorized f32 -> bf16 conversion, 8 elems/thread
__global__ void k_conv_w2(const float* __restrict__ src, ushort_t* __restrict__ dst, int n8) {
    int idx = blockIdx.x * 256 + threadIdx.x;
    if (idx < n8) {
        f32x4 a = *(const f32x4*)(src + (size_t)idx * 8);
        f32x4 b = *(const f32x4*)(src + (size_t)idx * 8 + 4);
        short8v o;
        o[0] = (short)f2bf(a[0]); o[1] = (short)f2bf(a[1]);
        o[2] = (short)f2bf(a[2]); o[3] = (short)f2bf(a[3]);
        o[4] = (short)f2bf(b[0]); o[5] = (short)f2bf(b[1]);
        o[6] = (short)f2bf(b[2]); o[7] = (short)f2bf(b[3]);
        *(short8v*)(dst + (size_t)idx * 8) = o;
    }
}

// ---------------- persistent pipelined scan (sentinel protocol — r5/r10) ------
template<int LAYER, int NKS>
__device__ __forceinline__ void lstm_body(
    int wg, int tid, const float* __restrict__ c0,
    float* __restrict__ wsf, float* __restrict__ outf,
    ushort_t* hA, ushort_t* hB, ushort_t* hS) {
    const int w = tid >> 6, lane = tid & 63, lr = lane & 15, lg = lane >> 4;
    const int g = lr & 3;
    const int K = NKS * 32;
    const ushort_t* WC = (const ushort_t*)(wsf + (LAYER == 0 ? OFF_WC1 : LAYER == 1 ? OFF_WC2 : OFF_WC3));
    ushort_t* H3b = (ushort_t*)(wsf + OFF_H3);
    const float* xg = outf + OUT_XG;
    ushort_t* rbase = (ushort_t*)(outf + OUT_RINGS);
    ushort_t* ringIn = rbase + (size_t)(LAYER == 0 ? 0 : LAYER - 1) * RING_STRIDE;
    ushort_t* ringOwn = rbase + (size_t)LAYER * RING_STRIDE;

    const int ccol = wg * 128 + 2 * w * 16 + lr;    // reordered col of tile 0, this lane
    short8v wr0[NKS], wr1[NKS];
    #pragma unroll
    for (int ks = 0; ks < NKS; ++ks) {
        wr0[ks] = *(const short8v*)(WC + (size_t)ccol * K + ks * 32 + lg * 8);
        wr1[ks] = *(const short8v*)(WC + (size_t)(ccol + 16) * K + ks * 32 + lg * 8);
    }
    float bs0 = 0.f, bs1 = 0.f;
    if (LAYER > 0) {
        const float* BS = wsf + (LAYER == 1 ? OFF_BS2 : OFF_BS3);
        bs0 = BS[ccol]; bs1 = BS[ccol + 16];
    }
    const int jj0 = w * 8 + (lr >> 2);              // col within wg's 32-col slice
    const int j0 = wg * 32 + jj0;
    f32x4 cst[4][2];
    #pragma unroll
    for (int i = 0; i < 4; ++i)
        #pragma unroll
        for (int r = 0; r < 4; ++r) {
            cst[i][0][r] = c0[(i * 16 + lg * 4 + r) * 256 + j0];
            cst[i][1][r] = c0[(i * 16 + lg * 4 + r) * 256 + j0 + 4];
        }

    // per-lane activation constants (own gate): g==2 -> tanh, else sigmoid
    const float sOwn = (g == 2) ? 2.f : -1.f;      // exp(sOwn * x)
    const float aOwn = (g == 2) ? -2.f : 1.f;      // act = aOwn*rcp(1+e) + bOwn
    const float bOwn = (g == 2) ? 1.f : 0.f;

    for (int t = 0; t < T_SEQ; ++t) {
        // ---- prefetch Xg (flag-independent; hides HBM latency under retries) ----
        f32x4 xpre[8];
        if (LAYER == 0) {
            const float* xt = xg + ((size_t)t * 1024 + wg * 128) * 64;
            #pragma unroll
            for (int i = 0; i < 4; ++i) {
                xpre[i]     = *(const f32x4*)(xt + (size_t)(2 * w * 16 + lr) * 64 + i * 16 + lg * 4);
                xpre[i + 4] = *(const f32x4*)(xt + (size_t)((2 * w + 1) * 16 + lr) * 64 + i * 16 + lg * 4);
            }
        }
        // ---- speculative load + sentinel retry ----
        i32x4 ta[8], tb[8];
        {
            const char* sA = (const char*)(LAYER == 0 ? (ringOwn + (size_t)t * SLOT)
                                                      : (ringIn + (size_t)(t + 1) * SLOT));
            const char* sB = (const char*)(ringOwn + (size_t)t * SLOT);
            bool bad;
            do {
                #pragma unroll
                for (int it = 0; it < 8; ++it)
                    ta[it] = bypass_ld128(sA + it * 4096 + tid * 16);
                if (LAYER > 0) {
                    #pragma unroll
                    for (int it = 0; it < 8; ++it)
                        tb[it] = bypass_ld128(sB + it * 4096 + tid * 16);
                }
                vm_drain();
                int p = 0;
                #pragma unroll
                for (int it = 0; it < 8; ++it)
                    p |= ((ta[it][0] & 0xFFFF) == POIS);
                if (LAYER > 0) {
                    #pragma unroll
                    for (int it = 0; it < 8; ++it)
                        p |= ((tb[it][0] & 0xFFFF) == POIS);
                }
                bad = __any(p);
            } while (bad);
        }
        __syncthreads();     // all waves done reading hA/hB of previous step
        // ---- restage to LDS (XOR swizzle) ----
        #pragma unroll
        for (int it = 0; it < 8; ++it) {
            int e16 = it * 256 + tid;
            int row = e16 >> 5, c16 = e16 & 31;
            int off = row * 512 + ((c16 ^ (row & 15)) << 4);
            *(i32x4*)((char*)hA + off) = ta[it];
            if (LAYER > 0) *(i32x4*)((char*)hB + off) = tb[it];
        }
        __syncthreads();
        // ---- acc init ----
        f32x4 acc[4][2];
        if (LAYER == 0) {
            #pragma unroll
            for (int i = 0; i < 4; ++i) { acc[i][0] = xpre[i]; acc[i][1] = xpre[i + 4]; }
        } else {
            #pragma unroll
            for (int i = 0; i < 4; ++i) {
                acc[i][0] = (f32x4){bs0, bs0, bs0, bs0};
                acc[i][1] = (f32x4){bs1, bs1, bs1, bs1};
            }
        }
        // ---- MFMA: gates += h_cat @ Wcat^T ----
        #pragma unroll
        for (int i = 0; i < 4; ++i) {
            #pragma unroll
            for (int ks = 0; ks < NKS; ++ks) {
                const ushort_t* hsrc = (ks < 8) ? hA : hB;
                const int krem = ks & 7;
                short8v a = *(const short8v*)((const char*)hsrc + (i * 16 + lr) * 512 +
                                              (((krem * 4 + lg) ^ lr) << 4));
                acc[i][0] = __builtin_amdgcn_mfma_f32_16x16x32_bf16(a, wr0[ks], acc[i][0], 0, 0, 0);
                acc[i][1] = __builtin_amdgcn_mfma_f32_16x16x32_bf16(a, wr1[ks], acc[i][1], 0, 0, 0);
            }
        }
        // ---- activations (own-gate act + DPP gather; scalar tanh for own row) ----
        #pragma unroll
        for (int i = 0; i < 4; ++i) {
            #pragma unroll
            for (int f = 0; f < 2; ++f) {
                f32x4 av = acc[i][f];
                f32x4 act;
                #pragma unroll
                for (int r = 0; r < 4; ++r) {
                    float e = __expf(sOwn * av[r]);
                    act[r] = fmaf(aOwn, __builtin_amdgcn_rcpf(1.f + e), bOwn);
                }
                f32x4 q1 = dpp4_x1(act), q2 = dpp4_x2(act), q3 = dpp4_x1(q2);
                f32x4 gI = (g == 0) ? act : (g == 1) ? q1 : (g == 2) ? q2 : q3;
                f32x4 gF = (g == 1) ? act : (g == 0) ? q1 : (g == 3) ? q2 : q3;
                f32x4 gG = (g == 2) ? act : (g == 3) ? q1 : (g == 0) ? q2 : q3;
                f32x4 gO = (g == 3) ? act : (g == 2) ? q1 : (g == 1) ? q2 : q3;
                f32x4 cv = gF * cst[i][f] + gI * gG;
                cst[i][f] = cv;
                float cg = (g == 0) ? cv[0] : (g == 1) ? cv[1] : (g == 2) ? cv[2] : cv[3];
                float go = (g == 0) ? gO[0] : (g == 1) ? gO[1] : (g == 2) ? gO[2] : gO[3];
                float e2 = __expf(2.f * cg);
                float th = fmaf(-2.f, __builtin_amdgcn_rcpf(1.f + e2), 1.f);
                float hval = go * th;
                int brow = i * 16 + lg * 4 + g;
                hS[brow * HSTR + jj0 + f * 4] = f2bf(hval);
            }
        }
        lgkm_drain();   // wave-local: hS rows for this wave's cols are complete
        // ---- readback own 8-col block rows, write-through to ring (+H3) ----
        {
            f32x4 hv4 = *(const f32x4*)((const char*)hS + lane * (HSTR * 2) + w * 16);
            bypass_st128(ringOwn + (size_t)(t + 1) * SLOT + (size_t)lane * 256 + wg * 32 + w * 8, hv4);
            if (LAYER == 2)
                *(f32x4*)(H3b + (((size_t)lane * 128 + t) * 256 + wg * 32 + w * 8)) = hv4;
        }
        // no drain, no flag — sentinel protocol; loop back to next step
    }
}

__global__ __launch_bounds__(256, 1) void k_lstm(const float* __restrict__ c0,
                                                 float* __restrict__ wsf,
                                                 float* __restrict__ outf) {
    __shared__ __align__(16) ushort_t hA[16384];
    __shared__ __align__(16) ushort_t hB[16384];
    __shared__ __align__(16) ushort_t hS[64 * HSTR];
    int layer = blockIdx.x >> 3, wg = blockIdx.x & 7;
    if (layer == 0)      lstm_body<0, 8>(wg, threadIdx.x, c0, wsf, outf, hA, hB, hS);
    else if (layer == 1) lstm_body<1, 16>(wg, threadIdx.x, c0, wsf, outf, hA, hB, hS);
    else                 lstm_body<2, 16>(wg, threadIdx.x, c0, wsf, outf, hA, hB, hS);
}

// ---------- head GEMM1 (MFMA): S1 = relu(H3 @ W1^T + b1) -> bf16 ----------
__global__ __launch_bounds__(256) void k_head1m(const ushort_t* __restrict__ H3,
                                                const ushort_t* __restrict__ W1B,
                                                const float* __restrict__ b1,
                                                ushort_t* __restrict__ S1) {
    __shared__ __align__(16) ushort_t As[128][32];
    __shared__ __align__(16) ushort_t Bs[128][32];
    int tid = threadIdx.x;
    int n0 = blockIdx.x * 128;      // 0 or 128
    int m0 = blockIdx.y * 128;      // 64 m-tiles
    int wave = tid >> 6, lane = tid & 63;
    int lr = lane & 15, lg = lane >> 4;
    int wm = (wave >> 1) * 64, wn = (wave & 1) * 64;
    f32x4 acc[4][4] = {};

    for (int kk = 0; kk < 256; kk += 32) {
        int id = tid;
        #pragma unroll
        for (int rep = 0; rep < 2; ++rep, id += 256) {
            int r = id >> 2, ch = (id & 3) * 8;
            *(short8v*)(&As[r][ch]) = *(const short8v*)(H3 + (size_t)(m0 + r) * 256 + kk + ch);
            *(short8v*)(&Bs[r][ch]) = *(const short8v*)(W1B + (size_t)(n0 + r) * 256 + kk + ch);
        }
        __syncthreads();
        short8v a[4], bb[4];
        #pragma unroll
        for (int i = 0; i < 4; ++i) a[i]  = *(const short8v*)(&As[wm + i * 16 + lr][lg * 8]);
        #pragma unroll
        for (int i = 0; i < 4; ++i) bb[i] = *(const short8v*)(&Bs[wn + i * 16 + lr][lg * 8]);
        #pragma unroll
        for (int i = 0; i < 4; ++i)
            #pragma unroll
            for (int f = 0; f < 4; ++f)
                acc[i][f] = __builtin_amdgcn_mfma_f32_16x16x32_bf16(a[i], bb[f], acc[i][f], 0, 0, 0);
        __syncthreads();
    }
    #pragma unroll
    for (int f = 0; f < 4; ++f) {
        int col = n0 + wn + f * 16 + lr;
        float bias = b1[col];
        #pragma unroll
        for (int i = 0; i < 4; ++i) {
            int rowb = m0 + wm + i * 16 + lg * 4;
            #pragma unroll
            for (int r = 0; r < 4; ++r)
                S1[(size_t)(rowb + r) * 256 + col] = f2bf(fmaxf(acc[i][f][r] + bias, 0.f));
        }
    }
}

// ---------- head GEMM2: scores = S1 @ W2^T + b2 (staged coalesced epilogue) ----
__global__ __launch_bounds__(256) void k_head2(const ushort_t* __restrict__ S1,
                                               const ushort_t* __restrict__ W2,
                                               const float* __restrict__ b2, float* __restrict__ out) {
    // As/Bs live during the K loop; the f32 [128][132] stage overlays them after.
    __shared__ __align__(16) char smem[67584];
    ushort_t (*As)[32] = (ushort_t (*)[32])smem;
    ushort_t (*Bs)[32] = (ushort_t (*)[32])(smem + 8192);
    float* stage = (float*)smem;          // [128][132] f32 (pad breaks row-bank alias)
    int tid = threadIdx.x;
    int n0 = blockIdx.x * 128;
    int m0 = blockIdx.y * 128;
    int wave = tid >> 6, lane = tid & 63;
    int lr = lane & 15, lg = lane >> 4;
    int wm = (wave >> 1) * 64, wn = (wave & 1) * 64;
    f32x4 acc[4][4] = {};

    for (int kk = 0; kk < 256; kk += 32) {
        int id = tid;
        #pragma unroll
        for (int rep = 0; rep < 2; ++rep, id += 256) {
            int r = id >> 2, ch = (id & 3) * 8;
            *(short8v*)(&As[r][ch]) = *(const short8v*)(S1 + (size_t)(m0 + r) * 256 + kk + ch);
            *(short8v*)(&Bs[r][ch]) = *(const short8v*)(W2 + (size_t)(n0 + r) * 256 + kk + ch);
        }
        __syncthreads();
        short8v a[4], bb[4];
        #pragma unroll
        for (int i = 0; i < 4; ++i) a[i]  = *(const short8v*)(&As[wm + i * 16 + lr][lg * 8]);
        #pragma unroll
        for (int i = 0; i < 4; ++i) bb[i] = *(const short8v*)(&Bs[wn + i * 16 + lr][lg * 8]);
        #pragma unroll
        for (int i = 0; i < 4; ++i)
            #pragma unroll
            for (int f = 0; f < 4; ++f)
                acc[i][f] = __builtin_amdgcn_mfma_f32_16x16x32_bf16(a[i], bb[f], acc[i][f], 0, 0, 0);
        __syncthreads();        // also protects the As/Bs -> stage overlay
    }
    // park bias-added results in LDS, then write full 512B rows coalesced + nt
    #pragma unroll
    for (int f = 0; f < 4; ++f) {
        int col = wn + f * 16 + lr;
        float bias = b2[n0 + col];
        #pragma unroll
        for (int i = 0; i < 4; ++i) {
            int rowl = wm + i * 16 + lg * 4;
            #pragma unroll
            for (int r = 0; r < 4; ++r)
                stage[(rowl + r) * 132 + col] = acc[i][f][r] + bias;
        }
    }
    __syncthreads();
    #pragma unroll
    for (int j = 0; j < 16; ++j) {
        int idx = j * 256 + tid;            // 4096 16B chunks = 128 rows x 512B
        int row = idx >> 5, c4 = idx & 31;
        f32x4 v = *(const f32x4*)(stage + row * 132 + c4 * 4);
        nt_st128(out + (size_t)(m0 + row) * VOCAB + n0 + c4 * 4, v);
    }
}

__global__ void k_labels(const int* __restrict__ tokens, float* __restrict__ out) {
    int i = blockIdx.x * 256 + threadIdx.x;
    if (i < BATCH * T_SEQ) out[i] = (float)tokens[i];
}

extern "C" void kernel_launch(void* const* d_in, const int* in_sizes, int n_in,
                              void* d_out, int out_size, void* d_ws, size_t ws_size,
                              hipStream_t stream) {
    const int*   tokens = (const int*)d_in[0];
    const float* h0   = (const float*)d_in[1];
    const float* c0   = (const float*)d_in[2];
    const float* emb  = (const float*)d_in[3];
    const float* Wih1 = (const float*)d_in[4];
    const float* Whh1 = (const float*)d_in[5];
    const float* bih1 = (const float*)d_in[6];
    const float* bhh1 = (const float*)d_in[7];
    const float* Wih2 = (const float*)d_in[8];
    const float* Whh2 = (const float*)d_in[9];
    const float* bih2 = (const float*)d_in[10];
    const float* bhh2 = (const float*)d_in[11];
    const float* Wih3 = (const float*)d_in[12];
    const float* Whh3 = (const float*)d_in[13];
    const float* bih3 = (const float*)d_in[14];
    const float* bhh3 = (const float*)d_in[15];
    const float* W1   = (const float*)d_in[16];
    const float* b1   = (const float*)d_in[17];
    const float* W2   = (const float*)d_in[18];
    const float* b2   = (const float*)d_in[19];

    float* ws  = (float*)d_ws;
    float* out = (float*)d_out;

    k_poison<<<12288, 256, 0, stream>>>((ushort_t*)(out + OUT_RINGS));
    k_reorder_w<<<3072, 256, 0, stream>>>(Whh1, Wih2, Whh2, Wih3, Whh3, ws);
    k_prep_small<<<328, 256, 0, stream>>>(bih2, bhh2, bih3, bhh3, h0, W1,
                                          ws, (ushort_t*)(out + OUT_RINGS));
    k_xg<<<dim3(128, 16), 256, 0, stream>>>(tokens, emb, Wih1, bih1, bhh1, out + OUT_XG);
    k_conv_w2<<<2000, 256, 0, stream>>>(W2, (ushort_t*)(ws + OFF_W2BF), VOCAB * 256 / 8);

    k_lstm<<<24, 256, 0, stream>>>(c0, ws, out);

    dim3 g1(2, 64);
    k_head1m<<<g1, 256, 0, stream>>>((const ushort_t*)(ws + OFF_H3),
                                     (const ushort_t*)(ws + OFF_W1BF), b1,
                                     (ushort_t*)(ws + OFF_S1));
    dim3 g2(125, 64);
    k_head2<<<g2, 256, 0, stream>>>((const ushort_t*)(ws + OFF_S1),
                                    (const ushort_t*)(ws + OFF_W2BF), b2, out);
    k_labels<<<32, 256, 0, stream>>>(tokens, out + (size_t)BATCH * T_SEQ * VOCAB);
}